// Round 13
// baseline (2134.144 us; speedup 1.0000x reference)
//
#include <hip/hip_runtime.h>

typedef unsigned short u16t;
typedef __attribute__((ext_vector_type(8))) short bf16x8;
typedef __attribute__((ext_vector_type(4))) float f32x4;
typedef __attribute__((ext_vector_type(2))) float f32x2;

#define DI static __device__ __forceinline__

constexpr int Bn = 256, Tn = 512;
constexpr long Rn = (long)Bn * Tn;   // 131072 rows = (b,t) pairs

DI float b2f(u16t u){ union{unsigned u32; float f;} v; v.u32 = ((unsigned)u)<<16; return v.f; }
DI u16t f2b(float f){ union{float fp; unsigned u;} v; v.fp=f; return (u16t)((v.u + 0x7fffu + ((v.u>>16)&1u))>>16); }
DI float fsigm(float x){ return __builtin_amdgcn_rcpf(1.f + __expf(-x)); }
DI float ftanh(float x){ float e = __expf(2.f*x); return 1.f - 2.f*__builtin_amdgcn_rcpf(e+1.f); }
DI float fgelu(float x){
  float t = 0.7978845608028654f*x*(1.f + 0.044715f*x*x);
  return x*(1.f - __builtin_amdgcn_rcpf(__expf(2.f*t)+1.f));
}
DI f32x4 mfma16(bf16x8 a, bf16x8 b, f32x4 c){ return __builtin_amdgcn_mfma_f32_16x16x32_bf16(a,b,c,0,0,0); }
// RNE pack: two fp32 -> one u32 of 2 bf16
DI unsigned pkr(float a, float b){ return (unsigned)f2b(a) | ((unsigned)f2b(b)<<16); }
DI float plo(unsigned u){ union{unsigned x; float f;} v; v.x = u<<16; return v.f; }
DI float phi(unsigned u){ union{unsigned x; float f;} v; v.x = u & 0xffff0000u; return v.f; }
DI bf16x8 mk8(unsigned w0,unsigned w1,unsigned w2,unsigned w3){
  union{unsigned u[4]; bf16x8 v;} z; z.u[0]=w0; z.u[1]=w1; z.u[2]=w2; z.u[3]=w3; return z.v;
}
// load 8 consecutive fp32 -> bf16x8 (RNE)
DI bf16x8 ldw8(const float* p){
  f32x4 a = *(const f32x4*)p, b = *(const f32x4*)(p+4);
  return mk8(pkr(a[0],a[1]), pkr(a[2],a[3]), pkr(b[0],b[1]), pkr(b[2],b[3]));
}
DI bf16x8 zero8(){ bf16x8 v; v[0]=0;v[1]=0;v[2]=0;v[3]=0;v[4]=0;v[5]=0;v[6]=0;v[7]=0; return v; }
// single-wave LDS fence: order LDS writes->reads without draining vmcnt (prefetch stays in flight)
DI void lfence(){ asm volatile("s_waitcnt lgkmcnt(0)" ::: "memory"); __builtin_amdgcn_sched_barrier(0); }

// ---------------- K1: MFMA pre-pass, 64 rows/block ----------------
// zfn (bf16, [row][32]) ; se1s (bf16, plain [row][128], bias included)
__global__ __launch_bounds__(256) void k_pre(
    const float* __restrict__ states, const float* __restrict__ nfast,
    const float* __restrict__ fe_w1, const float* __restrict__ fe_b1,
    const float* __restrict__ fe_w2, const float* __restrict__ fe_b2,
    const float* __restrict__ se_w1, const float* __restrict__ se_b1,
    u16t* __restrict__ ws_zfn, u16t* __restrict__ ws_se1)
{
  __shared__ __align__(16) u16t s_x[64*256];
  __shared__ __align__(16) u16t s_h[64*256];
  const int tid = threadIdx.x;
  const int lane = tid & 63, wave = tid >> 6;
  const int l15 = lane & 15, lh = lane >> 4;
  const long row0 = (long)blockIdx.x * 64;

  #pragma unroll
  for (int i=0;i<8;i++){
    int c = tid + i*256;
    int row = c >> 5, col = (c & 31) << 3;
    bf16x8 v = ldw8(states + (row0+row)*256 + col);
    *(bf16x8*)&s_x[row*256 + (col ^ ((row&7)<<3))] = v;
  }
  __syncthreads();

  const int wrow = wave*16;
  const int arow = wrow + l15;
  f32x4 acc1[16], acc3[8];
  #pragma unroll
  for (int nt=0;nt<16;nt++){ float bv = fe_b1[nt*16+l15]; acc1[nt] = (f32x4){bv,bv,bv,bv}; }
  #pragma unroll
  for (int nt=0;nt<8;nt++){ float bv = se_b1[nt*16+l15]; acc3[nt] = (f32x4){bv,bv,bv,bv}; }
  #pragma unroll
  for (int kt=0;kt<8;kt++){
    int acol = kt*32 + lh*8;
    bf16x8 af = *(const bf16x8*)&s_x[arow*256 + (acol ^ ((arow&7)<<3))];
    #pragma unroll
    for (int nt=0;nt<16;nt++){
      bf16x8 bw = ldw8(fe_w1 + (nt*16+l15)*256 + acol);
      acc1[nt] = mfma16(af, bw, acc1[nt]);
    }
    #pragma unroll
    for (int nt=0;nt<8;nt++){
      bf16x8 bw = ldw8(se_w1 + (nt*16+l15)*288 + acol);
      acc3[nt] = mfma16(af, bw, acc3[nt]);
    }
  }
  #pragma unroll
  for (int nt=0;nt<8;nt++){
    #pragma unroll
    for (int r=0;r<4;r++){
      int row = wrow + lh*4 + r;
      ws_se1[(row0+row)*128 + nt*16+l15] = f2b(acc3[nt][r]);
    }
  }
  #pragma unroll
  for (int nt=0;nt<16;nt++){
    #pragma unroll
    for (int r=0;r<4;r++){
      int row = wrow + lh*4 + r; int col = nt*16 + l15;
      s_h[row*256 + (col ^ ((row&7)<<3))] = f2b(fgelu(acc1[nt][r]));
    }
  }
  __syncthreads();
  f32x4 acc2[4];
  #pragma unroll
  for (int a=0;a<4;a++){ float bv = fe_b2[a*16+l15]; acc2[a] = (f32x4){bv,bv,bv,bv}; }
  #pragma unroll
  for (int kt=0;kt<8;kt++){
    int acol = kt*32 + lh*8;
    bf16x8 af = *(const bf16x8*)&s_h[arow*256 + (acol ^ ((arow&7)<<3))];
    #pragma unroll
    for (int a=0;a<4;a++){
      bf16x8 bw = ldw8(fe_w2 + (a*16+l15)*256 + acol);
      acc2[a] = mfma16(af, bw, acc2[a]);
    }
  }
  #pragma unroll
  for (int a=0;a<2;a++){
    #pragma unroll
    for (int r=0;r<4;r++){
      int row = wrow + lh*4 + r; int col = a*16 + l15;
      float nfv = nfast[(row0+row)*32 + col];
      float zv = acc2[a][r] + __expf(0.5f*acc2[a+2][r])*nfv;
      ws_zfn[(row0+row)*32 + col] = f2b(zv);
    }
  }
}

// ---------------- K2: recurrence — VALU, 256 blocks x 1 wave, 1 batch row/block ----------------
// Weights in VGPRs (bf16 pairs, RNE): zero LDS weight traffic, zero bank conflicts.
// Phase ordering via lfence (lgkmcnt only): prefetch global loads float across phases.
__global__ __launch_bounds__(64,1) void k_rec(
  const u16t* __restrict__ ws_zfn, const u16t* __restrict__ ws_se1,
  const float* __restrict__ actions, const float* __restrict__ noise_slow,
  const float* __restrict__ fg_wih, const float* __restrict__ fg_whh,
  const float* __restrict__ fg_bih, const float* __restrict__ fg_bhh,
  const float* __restrict__ se_w1, const float* __restrict__ se_w2, const float* __restrict__ se_b2,
  const float* __restrict__ sg_wih, const float* __restrict__ sg_whh,
  const float* __restrict__ sg_bih, const float* __restrict__ sg_bhh,
  const float* __restrict__ updp,
  float* __restrict__ out_zf, float* __restrict__ out_zs)
{
  __shared__ __align__(16) float zfv[32], zsv[16], zfnv[32], actv[4], nsv[16];
  __shared__ __align__(16) float se1v[128], hidv[128], zsnv[16], spb[32];
  __shared__ __align__(16) float gsum[64], gni[32], gnh[32], sgib[48], sghb[48];
  const int lane = threadIdx.x;
  const int l31 = lane & 31, hf = lane >> 5;
  const long base = (long)blockIdx.x * Tn;

  // ---- per-lane weights in registers (bf16 pairs, RNE) ----
  unsigned wihP[18], whhP[16], wihH[9], whhH[8], wseP[2][16], wspP[32], wsgiP[24], wsghP[8];
  #pragma unroll
  for (int p=0;p<18;p++) wihP[p] = pkr(fg_wih[lane*36+2*p], fg_wih[lane*36+2*p+1]);
  #pragma unroll
  for (int p=0;p<16;p++) whhP[p] = pkr(fg_whh[lane*32+2*p], fg_whh[lane*32+2*p+1]);
  #pragma unroll
  for (int p=0;p<9;p++){ int k = hf*18+2*p;
    wihH[p] = pkr(fg_wih[(64+l31)*36 + k], fg_wih[(64+l31)*36 + k+1]); }
  #pragma unroll
  for (int p=0;p<8;p++){ int k = hf*16+2*p;
    whhH[p] = pkr(fg_whh[(64+l31)*32 + k], fg_whh[(64+l31)*32 + k+1]); }
  #pragma unroll
  for (int jj=0;jj<2;jj++){
    #pragma unroll
    for (int p=0;p<16;p++)
      wseP[jj][p] = pkr(se_w1[(lane+jj*64)*288 + 256 + 2*p], se_w1[(lane+jj*64)*288 + 256 + 2*p+1]);
  }
  #pragma unroll
  for (int p=0;p<32;p++)
    wspP[p] = pkr(se_w2[l31*128 + hf*64 + 2*p], se_w2[l31*128 + hf*64 + 2*p+1]);
  if (lane < 48){
    #pragma unroll
    for (int p=0;p<24;p++) wsgiP[p] = pkr(sg_wih[lane*48+2*p], sg_wih[lane*48+2*p+1]);
    #pragma unroll
    for (int p=0;p<8;p++)  wsghP[p] = pkr(sg_whh[lane*16+2*p], sg_whh[lane*16+2*p+1]);
  }
  const float bsum  = fg_bih[lane] + fg_bhh[lane];
  const float bni2  = fg_bih[64+l31], bnh2 = fg_bhh[64+l31];
  const float seb2L = se_b2[l31];
  const float sgbiL = sg_bih[lane<48?lane:47], sgbhL = sg_bhh[lane<48?lane:47];
  const float upd = fsigm(updp[0]);

  if (lane < 32) zfv[lane] = 0.f;
  if (lane < 16) zsv[lane] = 0.f;

  u16t pzfn = 0, ps0 = 0, ps1 = 0; float pact = 0.f, pns = 0.f;
  auto pf = [&](int tt){
    if (lane < 32) pzfn = ws_zfn[(base+tt)*32 + lane];
    ps0 = ws_se1[(base+tt)*128 + lane];
    ps1 = ws_se1[(base+tt)*128 + 64 + lane];
    if (lane < 4)  pact = actions[(base+tt)*4 + lane];
    if (lane < 16) pns  = noise_slow[(base+tt)*16 + lane];
  };
  pf(0);

  for (int t=0; t<Tn; t++){
    // commit step-t inputs to LDS
    if (lane < 32) zfnv[lane] = b2f(pzfn);
    se1v[lane] = b2f(ps0); se1v[64+lane] = b2f(ps1);
    if (lane < 4)  actv[lane] = pact;
    if (lane < 16) nsv[lane] = pns;
    lfence();
    if (t+1 < Tn) pf(t+1);   // regs only; consumed at next commit (vmcnt handled by compiler)

    // P1: fast-GRU gate pre-activations
    {
      float s = bsum;
      #pragma unroll
      for (int p=0;p<18;p++){
        f32x2 x = (p<16) ? *(const f32x2*)&zfnv[2*p] : *(const f32x2*)&actv[2*(p-16)];
        s += plo(wihP[p])*x[0] + phi(wihP[p])*x[1];
      }
      #pragma unroll
      for (int p=0;p<16;p++){
        f32x2 x = *(const f32x2*)&zfv[2*p];
        s += plo(whhP[p])*x[0] + phi(whhP[p])*x[1];
      }
      gsum[lane] = s;
      float si = 0.f, sh = 0.f;
      #pragma unroll
      for (int p=0;p<9;p++){
        int k = hf*18 + 2*p;
        f32x2 x = (k < 32) ? *(const f32x2*)&zfnv[k] : *(const f32x2*)&actv[k-32];
        si += plo(wihH[p])*x[0] + phi(wihH[p])*x[1];
      }
      #pragma unroll
      for (int p=0;p<8;p++){
        f32x2 x = *(const f32x2*)&zfv[hf*16 + 2*p];
        sh += plo(whhH[p])*x[0] + phi(whhH[p])*x[1];
      }
      si += __shfl_xor(si, 32);
      sh += __shfl_xor(sh, 32);
      if (lane < 32){ gni[lane] = si + bni2; gnh[lane] = sh + bnh2; }
    }
    lfence();
    // P1b: zf update
    if (lane < 32){
      float r = fsigm(gsum[lane]);
      float z = fsigm(gsum[32+lane]);
      float n = ftanh(gni[lane] + r*gnh[lane]);
      float h2 = (1.f-z)*n + z*zfv[lane];
      zfv[lane] = h2;
      out_zf[(base+t)*32 + lane] = h2;
    }
    lfence();
    // P2: slow-encoder hidden
    #pragma unroll
    for (int jj=0;jj<2;jj++){
      float s = se1v[lane + jj*64];
      #pragma unroll
      for (int p=0;p<16;p++){
        f32x2 x = *(const f32x2*)&zfv[2*p];
        s += plo(wseP[jj][p])*x[0] + phi(wseP[jj][p])*x[1];
      }
      hidv[lane + jj*64] = fgelu(s);
    }
    lfence();
    // P3: sp = hid @ se_w2^T + b2 (half-split dots)
    {
      float s = 0.f;
      #pragma unroll
      for (int p=0;p<32;p++){
        f32x2 x = *(const f32x2*)&hidv[hf*64 + 2*p];
        s += plo(wspP[p])*x[0] + phi(wspP[p])*x[1];
      }
      s += __shfl_xor(s, 32);
      if (lane < 32) spb[lane] = s + seb2L;
    }
    lfence();
    if (lane < 16) zsnv[lane] = spb[lane] + __expf(0.5f*spb[16+lane])*nsv[lane];
    lfence();
    // P4: slow-GRU gates
    if (lane < 48){
      float gi = sgbiL, gh = sgbhL;
      #pragma unroll
      for (int p=0;p<24;p++){
        f32x2 x = (p<8) ? *(const f32x2*)&zsnv[2*p] : *(const f32x2*)&zfv[2*p-16];
        gi += plo(wsgiP[p])*x[0] + phi(wsgiP[p])*x[1];
      }
      #pragma unroll
      for (int p=0;p<8;p++){
        f32x2 x = *(const f32x2*)&zsv[2*p];
        gh += plo(wsghP[p])*x[0] + phi(wsghP[p])*x[1];
      }
      sgib[lane] = gi; sghb[lane] = gh;
    }
    lfence();
    // P4b: zs update + blend
    if (lane < 16){
      float r = fsigm(sgib[lane] + sghb[lane]);
      float z = fsigm(sgib[16+lane] + sghb[16+lane]);
      float n = ftanh(sgib[32+lane] + r*sghb[32+lane]);
      float zt = (1.f-z)*n + z*zsv[lane];
      float zn = upd*zt + (1.f-upd)*zsv[lane];
      zsv[lane] = zn;
      out_zs[(base+t)*16 + lane] = zn;
    }
    lfence();
  }
}

// ---------------- K3: MFMA decoder, 64 rows/block, fp32 in/out ----------------
__global__ __launch_bounds__(256) void k_dec(
  const float* __restrict__ izf, const float* __restrict__ izs,
  const float* __restrict__ de_w1, const float* __restrict__ de_b1,
  const float* __restrict__ de_w2, const float* __restrict__ de_b2,
  float* __restrict__ preds)
{
  __shared__ __align__(16) u16t s_a[64*64];
  __shared__ __align__(16) u16t s_h[64*256];
  const int tid = threadIdx.x;
  const int lane = tid & 63, wave = tid >> 6;
  const int l15 = lane & 15, lh = lane >> 4;
  const long row0 = (long)blockIdx.x * 64;

  { int row = tid >> 2, col = (tid & 3) << 3;
    bf16x8 v = ldw8(izf + (row0+row)*32 + col);
    *(bf16x8*)&s_a[row*64 + (col ^ ((row&7)<<3))] = v; }
  if (tid < 128){
    int row = tid >> 1, col = 32 + ((tid & 1) << 3);
    bf16x8 v = ldw8(izs + (row0+row)*16 + ((tid&1)<<3));
    *(bf16x8*)&s_a[row*64 + (col ^ ((row&7)<<3))] = v;
  } else {
    int t2 = tid - 128;
    int row = t2 >> 1, col = 48 + ((t2 & 1) << 3);
    bf16x8 v = zero8();
    *(bf16x8*)&s_a[row*64 + (col ^ ((row&7)<<3))] = v;
  }
  __syncthreads();

  const int wrow = wave*16;
  const int arow = wrow + l15;
  f32x4 acc[16];
  #pragma unroll
  for (int nt=0;nt<16;nt++){ float bv = de_b1[nt*16+l15]; acc[nt] = (f32x4){bv,bv,bv,bv}; }
  #pragma unroll
  for (int kt=0;kt<2;kt++){
    int acol = kt*32 + lh*8;
    bf16x8 af = *(const bf16x8*)&s_a[arow*64 + (acol ^ ((arow&7)<<3))];
    #pragma unroll
    for (int nt=0;nt<16;nt++){
      bf16x8 bw = zero8();
      if (!(kt==1 && lh>=2)) bw = ldw8(de_w1 + (nt*16+l15)*48 + acol);
      acc[nt] = mfma16(af, bw, acc[nt]);
    }
  }
  #pragma unroll
  for (int nt=0;nt<16;nt++){
    #pragma unroll
    for (int r=0;r<4;r++){
      int row = wrow + lh*4 + r; int col = nt*16 + l15;
      s_h[row*256 + (col ^ ((row&7)<<3))] = f2b(fgelu(acc[nt][r]));
    }
  }
  __syncthreads();
  f32x4 a2[16];
  #pragma unroll
  for (int nt=0;nt<16;nt++){ float bv = de_b2[nt*16+l15]; a2[nt] = (f32x4){bv,bv,bv,bv}; }
  #pragma unroll
  for (int kt=0;kt<8;kt++){
    int acol = kt*32 + lh*8;
    bf16x8 af = *(const bf16x8*)&s_h[arow*256 + (acol ^ ((arow&7)<<3))];
    #pragma unroll
    for (int nt=0;nt<16;nt++){
      bf16x8 bw = ldw8(de_w2 + (nt*16+l15)*256 + acol);
      a2[nt] = mfma16(af, bw, a2[nt]);
    }
  }
  #pragma unroll
  for (int nt=0;nt<16;nt++){
    #pragma unroll
    for (int r=0;r<4;r++){
      int row = wrow + lh*4 + r;
      preds[(row0+row)*256 + nt*16+l15] = a2[nt][r];
    }
  }
}

extern "C" void kernel_launch(void* const* d_in, const int* in_sizes, int n_in,
                              void* d_out, int out_size, void* d_ws, size_t ws_size,
                              hipStream_t stream)
{
  if (n_in < 25 || in_sizes[0] != (int)(Rn*256) || in_sizes[8] != 96*36 ||
      in_sizes[12] != 128*288 || in_sizes[20] != 256*48 || in_sizes[24] != 1)
    return;
  if (out_size != (int)(Rn*304))
    return;

  const float* states = (const float*)d_in[0];
  const float* actions= (const float*)d_in[1];
  const float* nfast  = (const float*)d_in[2];
  const float* nslow  = (const float*)d_in[3];
  const float* fe_w1  = (const float*)d_in[4];
  const float* fe_b1  = (const float*)d_in[5];
  const float* fe_w2  = (const float*)d_in[6];
  const float* fe_b2  = (const float*)d_in[7];
  const float* fg_wih = (const float*)d_in[8];
  const float* fg_whh = (const float*)d_in[9];
  const float* fg_bih = (const float*)d_in[10];
  const float* fg_bhh = (const float*)d_in[11];
  const float* se_w1  = (const float*)d_in[12];
  const float* se_b1  = (const float*)d_in[13];
  const float* se_w2  = (const float*)d_in[14];
  const float* se_b2  = (const float*)d_in[15];
  const float* sg_wih = (const float*)d_in[16];
  const float* sg_whh = (const float*)d_in[17];
  const float* sg_bih = (const float*)d_in[18];
  const float* sg_bhh = (const float*)d_in[19];
  const float* de_w1  = (const float*)d_in[20];
  const float* de_b1  = (const float*)d_in[21];
  const float* de_w2  = (const float*)d_in[22];
  const float* de_b2  = (const float*)d_in[23];
  const float* updp   = (const float*)d_in[24];

  // d_out is FP32: [preds | zf | zs] flat.
  float* preds = (float*)d_out;
  float* ozf = preds + Rn*256;
  float* ozs = ozf + Rn*32;

  // Scratch: zfn bf16 [Rn][32] + se1 bf16 [Rn][128] = Rn*320 bytes.
  size_t need = (size_t)Rn*320;
  u16t* ws_zfn; u16t* ws_se1;
  if (ws_size >= need){
    ws_zfn = (u16t*)d_ws;
    ws_se1 = ws_zfn + Rn*32;
  } else {
    ws_zfn = (u16t*)preds;   // alias inside preds fp32 region; k_dec overwrites after
    ws_se1 = ws_zfn + Rn*32;
  }

  k_pre<<<(int)(Rn/64), 256, 0, stream>>>(states, nfast,
      fe_w1, fe_b1, fe_w2, fe_b2, se_w1, se_b1, ws_zfn, ws_se1);
  k_rec<<<Bn, 64, 0, stream>>>(ws_zfn, ws_se1, actions, nslow,
      fg_wih, fg_whh, fg_bih, fg_bhh, se_w1, se_w2, se_b2,
      sg_wih, sg_whh, sg_bih, sg_bhh, updp, ozf, ozs);
  k_dec<<<(int)(Rn/64), 256, 0, stream>>>(ozf, ozs, de_w1, de_b1, de_w2, de_b2, preds);
}